// Round 10
// baseline (1252.055 us; speedup 1.0000x reference)
//
#include <hip/hip_runtime.h>
#include <hip/hip_bf16.h>

// Window attention (Swin-style), MI355X gfx950. v10: barrier-free two-kernel.
//  K1 (winattn_attn): grid 65536 x 64 threads; block = one (window, head).
//    af from global (v7) -> per-head QKV (v9 t-loop) -> Q/K in 6272B LDS
//    (wave-private, P aliases) -> scores+softmax (v9) -> PV swapped (v5
//    algebra) -> AO bf16 stored in the UPPER HALF of the window's d_out slot
//    (bytes +12544..25088). ZERO barriers; 16 independent waves/CU.
//  K2 (winattn_proj): grid 16384 x 64 threads; no LDS, no barriers. AO
//    fragments straight from global (all loads drain before first MFMA, so
//    the out-store overwrite of the AO region is safe), proj GEMM, v4-proven
//    scalar unswapped stores (1x HBM write; float4-swapped measured 2x).

#define NTOK 49
#define DIMC 128
#define NWM  1024
#define SCALE 0.17677669529663687f

typedef __attribute__((ext_vector_type(8))) __bf16 bf16x8;
typedef __attribute__((ext_vector_type(4))) float f32x4;

#define K1_SMEM 6272   // Q[49][64B] @0 + K[49][64B] @3136; P[49][128B] aliases

__device__ __forceinline__ unsigned short f2bf(float f) {
  union { float f; unsigned u; } x; x.f = f;
  unsigned r = x.u + 0x7fffu + ((x.u >> 16) & 1u);   // round-to-nearest-even
  return (unsigned short)(r >> 16);
}

__device__ __forceinline__ unsigned pk2(float a, float b) {
  __hip_bfloat162 t = __float22bfloat162_rn(make_float2(a, b));
  union { __hip_bfloat162 h; unsigned u; } c; c.h = t;
  return c.u;
}

__device__ __forceinline__ f32x4 mfma16(bf16x8 a, bf16x8 b, f32x4 c) {
  return __builtin_amdgcn_mfma_f32_16x16x32_bf16(a, b, c, 0, 0, 0);
}

__device__ __forceinline__ bf16x8 zero8() {
  bf16x8 z;
#pragma unroll
  for (int j = 0; j < 8; ++j) z[j] = (__bf16)0.f;
  return z;
}

// prep: weights -> bf16; rel-pos bias pre-gathered into padded [4][64][64] f32
// with -1e30 outside the 49x49 valid square (kills padding through softmax).
__global__ void winattn_prep(const float* __restrict__ qkv_w,
                             const float* __restrict__ proj_w,
                             const float* __restrict__ table,
                             const int* __restrict__ ridx,
                             unsigned short* __restrict__ qkv_wb,
                             unsigned short* __restrict__ proj_wb,
                             float* __restrict__ bias_g) {
  int i = blockIdx.x * 256 + threadIdx.x;
  if (i < 384 * DIMC) qkv_wb[i] = f2bf(qkv_w[i]);
  if (i < DIMC * DIMC) proj_wb[i] = f2bf(proj_w[i]);
  if (i < 4 * 64 * 64) {
    int h = i >> 12, n = (i >> 6) & 63, m = i & 63;
    float v = -1e30f;
    if (n < NTOK && m < NTOK) v = table[ridx[n * NTOK + m] * 4 + h];
    bias_g[i] = v;
  }
}

// ---------------- K1: per-(window,head) attention, barrier-free ------------
__launch_bounds__(64, 4)
__global__ void winattn_attn(const float* __restrict__ x,
                             const float* __restrict__ mask,
                             const unsigned short* __restrict__ qkv_wb,
                             const float* __restrict__ qkv_b,
                             const float* __restrict__ bias_g,
                             float* __restrict__ outF) {
  __shared__ char smem[K1_SMEM] __attribute__((aligned(128)));
  const int bid  = blockIdx.x;
  const int w    = bid >> 2;
  const int h    = bid & 3;
  const int lane = threadIdx.x & 63;
  const int lr   = lane & 15;
  const int lg   = lane >> 4;
  const f32x4 fzero = {0.f, 0.f, 0.f, 0.f};

  const float* xw = x + (size_t)w * (NTOK * DIMC);

  // ---------- af fragments directly from global x (v7 verbatim) -----------
  bf16x8 af[4][4];
#pragma unroll
  for (int mt = 0; mt < 4; ++mt)
#pragma unroll
    for (int kk = 0; kk < 4; ++kk) {
      int n = mt * 16 + lr;
      bool pad = (n > 48);
      int nc = pad ? 48 : n;
      const float* src = xw + nc * DIMC + kk * 32 + lg * 8;
      float4 v0 = *reinterpret_cast<const float4*>(src);
      float4 v1 = *reinterpret_cast<const float4*>(src + 4);
      uint4 d;
      d.x = pk2(v0.x, v0.y); d.y = pk2(v0.z, v0.w);
      d.z = pk2(v1.x, v1.y); d.w = pk2(v1.z, v1.w);
      union { uint4 u; bf16x8 b; } cvt; cvt.u = d;
      af[mt][kk] = pad ? zero8() : cvt.b;
    }

  // ---------- Stage B: q,k,v of head h (v9 t-loop, hb=0) ------------------
  bf16x8 vb[2][2];   // PV A-fragments (V^T), built in-register
#pragma unroll
  for (int t = 0; t < 6; ++t) {
    const int sec  = t >> 1;                   // 0=q 1=k 2=v
    const int half = t & 1;                    // d-half (0..15 / 16..31)
    const int o0   = sec * 128 + 32 * h + 16 * half;
    const unsigned short* wrow = qkv_wb + (o0 + lr) * DIMC;
    bf16x8 wf[4];
#pragma unroll
    for (int kk = 0; kk < 4; ++kk)
      wf[kk] = *reinterpret_cast<const bf16x8*>(wrow + kk * 32 + 8 * lg);
    f32x4 acc[4];
#pragma unroll
    for (int mt = 0; mt < 4; ++mt) acc[mt] = fzero;
#pragma unroll
    for (int kk = 0; kk < 4; ++kk)
#pragma unroll
      for (int mt = 0; mt < 4; ++mt)
        acc[mt] = mfma16(af[mt][kk], wf[kk], acc[mt]);   // unswapped (proven)
    const float bq = qkv_b[o0 + lr];
    const int d = 16 * half + lr;
    if (sec < 2) {
      const int base = (sec == 1) ? 3136 : 0;
#pragma unroll
      for (int mt = 0; mt < 4; ++mt)
#pragma unroll
        for (int r = 0; r < 4; ++r) {
          const int n = mt * 16 + lg * 4 + r;  // token
          if (n < NTOK) {
            int mb = (d * 2) ^ ((n & 3) << 4);
            *reinterpret_cast<unsigned short*>(smem + base + n * 64 + mb) =
                f2bf(acc[mt][r] + bq);
          }
        }
    } else {
      // V-in-register shfl quad-gather (v9-proven)
      uint2 pk[4];
#pragma unroll
      for (int mt = 0; mt < 4; ++mt) {
        pk[mt].x = pk2(acc[mt][0] + bq, acc[mt][1] + bq);
        pk[mt].y = pk2(acc[mt][2] + bq, acc[mt][3] + bq);
      }
      const int srcLow  = lr + ((lg & 1) ? 32 : 0);
      const int srcHigh = srcLow + 16;
      const bool hiSel  = (lg >> 1) != 0;
#pragma unroll
      for (int kk = 0; kk < 2; ++kk) {
        unsigned a0x = __shfl(pk[kk * 2].x, srcLow);
        unsigned a0y = __shfl(pk[kk * 2].y, srcLow);
        unsigned a1x = __shfl(pk[kk * 2 + 1].x, srcLow);
        unsigned a1y = __shfl(pk[kk * 2 + 1].y, srcLow);
        unsigned b0x = __shfl(pk[kk * 2].x, srcHigh);
        unsigned b0y = __shfl(pk[kk * 2].y, srcHigh);
        unsigned b1x = __shfl(pk[kk * 2 + 1].x, srcHigh);
        unsigned b1y = __shfl(pk[kk * 2 + 1].y, srcHigh);
        union { uint4 u; bf16x8 b; } cvt;
        cvt.u.x = hiSel ? a1x : a0x;
        cvt.u.y = hiSel ? a1y : a0y;
        cvt.u.z = hiSel ? b1x : b0x;
        cvt.u.w = hiSel ? b1y : b0y;
        vb[half][kk] = cvt.b;   // V^T[d'=16*half+lr][tokens kk*32+lg*8..+7]
      }
    }
  }
  // everything wave-private -> no barrier anywhere

  // ---------- Stage C: scores + softmax (v9 verbatim, hb=0) ---------------
  {
    bf16x8 qf[4], kf[4];
#pragma unroll
    for (int mt = 0; mt < 4; ++mt) {
      int n = mt * 16 + lr; if (n > 48) n = 48;
      int mb = (lg * 16) ^ ((n & 3) << 4);
      qf[mt] = *reinterpret_cast<const bf16x8*>(smem + n * 64 + mb);
    }
#pragma unroll
    for (int nt = 0; nt < 4; ++nt) {
      int m = nt * 16 + lr; if (m > 48) m = 48;
      int mb = (lg * 16) ^ ((m & 3) << 4);
      kf[nt] = *reinterpret_cast<const bf16x8*>(smem + 3136 + m * 64 + mb);
    }
    f32x4 sc[4][4];
#pragma unroll
    for (int mt = 0; mt < 4; ++mt)
#pragma unroll
      for (int nt = 0; nt < 4; ++nt)
        sc[mt][nt] = mfma16(qf[mt], kf[nt], fzero);

    const float* bgh = bias_g + h * 4096;
    const float* mw  = mask + (size_t)(w & (NWM - 1)) * (NTOK * NTOK);
#pragma unroll
    for (int mt = 0; mt < 4; ++mt)
#pragma unroll
      for (int r = 0; r < 4; ++r) {
        const int n  = mt * 16 + lg * 4 + r;
        const int nc = (n > 48) ? 48 : n;
#pragma unroll
        for (int nt = 0; nt < 4; ++nt) {
          const int m  = nt * 16 + lr;
          const int mc = (m > 48) ? 48 : m;
          sc[mt][nt][r] = sc[mt][nt][r] * SCALE + bgh[n * 64 + m] + mw[nc * NTOK + mc];
        }
      }
    // softmax per row n (v9 verbatim)
#pragma unroll
    for (int mt = 0; mt < 4; ++mt)
#pragma unroll
      for (int r = 0; r < 4; ++r) {
        float mx = sc[mt][0][r];
#pragma unroll
        for (int nt = 1; nt < 4; ++nt) mx = fmaxf(mx, sc[mt][nt][r]);
        mx = fmaxf(mx, __shfl_xor(mx, 1, 16));
        mx = fmaxf(mx, __shfl_xor(mx, 2, 16));
        mx = fmaxf(mx, __shfl_xor(mx, 4, 16));
        mx = fmaxf(mx, __shfl_xor(mx, 8, 16));
        float e[4]; float sum = 0.f;
#pragma unroll
        for (int nt = 0; nt < 4; ++nt) { e[nt] = __expf(sc[mt][nt][r] - mx); sum += e[nt]; }
        sum += __shfl_xor(sum, 1, 16);
        sum += __shfl_xor(sum, 2, 16);
        sum += __shfl_xor(sum, 4, 16);
        sum += __shfl_xor(sum, 8, 16);
        const float inv = __builtin_amdgcn_rcpf(sum);
        const int n = mt * 16 + lg * 4 + r;
        if (n < NTOK) {
#pragma unroll
          for (int nt = 0; nt < 4; ++nt) {
            const int m = nt * 16 + lr;
            int mb = (m * 2) ^ ((n & 7) << 4);
            *reinterpret_cast<unsigned short*>(smem + n * 128 + mb) =
                f2bf(e[nt] * inv);   // P aliases Q+K (same-wave, v9-proven)
          }
        }
      }
  }

  // ---------- Stage D: PV swapped (v5 algebra) -> AO bf16 to global -------
  {
    bf16x8 pa[4][2];
#pragma unroll
    for (int nt = 0; nt < 4; ++nt)
#pragma unroll
      for (int kk = 0; kk < 2; ++kk) {
        int n = nt * 16 + lr; if (n > 48) n = 48;
        int mb = (kk * 64 + lg * 16) ^ ((n & 7) << 4);
        pa[nt][kk] = *reinterpret_cast<const bf16x8*>(smem + n * 128 + mb);
      }
    f32x4 oc[2][4];
#pragma unroll
    for (int dt = 0; dt < 2; ++dt)
#pragma unroll
      for (int nt = 0; nt < 4; ++nt) oc[dt][nt] = fzero;
#pragma unroll
    for (int kk = 0; kk < 2; ++kk)
#pragma unroll
      for (int dt = 0; dt < 2; ++dt)
#pragma unroll
        for (int nt = 0; nt < 4; ++nt)
          oc[dt][nt] = mfma16(vb[dt][kk], pa[nt][kk], oc[dt][nt]);
    // lane (lr,lg) reg r: AO[n = nt*16+lr][c = 32h+16dt+4lg+r]
    char* aoBase = reinterpret_cast<char*>(outF) + (size_t)w * 25088 + 12544;
#pragma unroll
    for (int dt = 0; dt < 2; ++dt)
#pragma unroll
      for (int nt = 0; nt < 4; ++nt) {
        int n = nt * 16 + lr;
        if (n < NTOK) {
          unsigned lo = pk2(oc[dt][nt][0], oc[dt][nt][1]);
          unsigned hi = pk2(oc[dt][nt][2], oc[dt][nt][3]);
          *reinterpret_cast<uint2*>(aoBase + n * 256 + 64 * h + 32 * dt + 8 * lg) =
              make_uint2(lo, hi);
        }
      }
  }
}

// ---------------- K2: proj GEMM per window, no LDS, no barriers ------------
__launch_bounds__(64, 8)
__global__ void winattn_proj(const unsigned short* __restrict__ proj_wb,
                             const float* __restrict__ proj_b,
                             float* __restrict__ outF) {
  const int w    = blockIdx.x;
  const int lane = threadIdx.x & 63;
  const int lr   = lane & 15;
  const int lg   = lane >> 4;
  const f32x4 fzero = {0.f, 0.f, 0.f, 0.f};

  const char* aoBase = reinterpret_cast<const char*>(outF) + (size_t)w * 25088 + 12544;

  // AO fragments straight from global (v7 af pattern). ALL 16 loads are
  // consumed by the first ct's MFMAs -> vmcnt drains before any store below
  // overwrites the AO region.
  bf16x8 aof[4][4];
#pragma unroll
  for (int mt = 0; mt < 4; ++mt)
#pragma unroll
    for (int kk = 0; kk < 4; ++kk) {
      int n = mt * 16 + lr; if (n > 48) n = 48;
      aof[mt][kk] = *reinterpret_cast<const bf16x8*>(
          aoBase + n * 256 + (kk * 32 + lg * 8) * 2);
    }

  float* ow = outF + (size_t)w * (NTOK * DIMC);
#pragma unroll
  for (int ct = 0; ct < 8; ++ct) {
    const int c = ct * 16 + lr;
    const unsigned short* wrow = proj_wb + c * DIMC;
    bf16x8 wf[4];
#pragma unroll
    for (int kk = 0; kk < 4; ++kk)
      wf[kk] = *reinterpret_cast<const bf16x8*>(wrow + kk * 32 + lg * 8);
    f32x4 acc[4];
#pragma unroll
    for (int mt = 0; mt < 4; ++mt) acc[mt] = fzero;
#pragma unroll
    for (int kk = 0; kk < 4; ++kk)
#pragma unroll
      for (int mt = 0; mt < 4; ++mt)
        acc[mt] = mfma16(aof[mt][kk], wf[kk], acc[mt]);   // unswapped
    const float bp = proj_b[c];
#pragma unroll
    for (int mt = 0; mt < 4; ++mt)
#pragma unroll
      for (int r = 0; r < 4; ++r) {
        const int n = mt * 16 + lg * 4 + r;
        if (n < NTOK) ow[n * DIMC + c] = acc[mt][r] + bp;   // v4 scalar (1x write)
      }
  }
}

extern "C" void kernel_launch(void* const* d_in, const int* in_sizes, int n_in,
                              void* d_out, int out_size, void* d_ws, size_t ws_size,
                              hipStream_t stream) {
  const float* x      = (const float*)d_in[0];
  const float* mask   = (const float*)d_in[1];
  const float* qkv_w  = (const float*)d_in[2];
  const float* qkv_b  = (const float*)d_in[3];
  const float* proj_w = (const float*)d_in[4];
  const float* proj_b = (const float*)d_in[5];
  const float* table  = (const float*)d_in[6];
  const int*   ridx   = (const int*)d_in[7];

  unsigned short* qkv_wb  = (unsigned short*)d_ws;           // 384*128 bf16
  unsigned short* proj_wb = qkv_wb + 384 * DIMC;             // 128*128 bf16
  float*          bias_g  = (float*)(proj_wb + DIMC * DIMC); // [4][64][64] f32

  winattn_prep<<<192, 256, 0, stream>>>(qkv_w, proj_w, table, ridx,
                                        qkv_wb, proj_wb, bias_g);

  const int nwin = in_sizes[0] / (NTOK * DIMC);
  winattn_attn<<<nwin * 4, 64, 0, stream>>>(x, mask, qkv_wb, qkv_b, bias_g,
                                            (float*)d_out);
  winattn_proj<<<nwin, 64, 0, stream>>>(proj_wb, proj_b, (float*)d_out);
}

// Round 11
// 654.266 us; speedup vs baseline: 1.9137x; 1.9137x over previous
//
#include <hip/hip_runtime.h>
#include <hip/hip_bf16.h>

// Window attention (Swin-style), MI355X gfx950. v11 = v4 (549us champion)
// with the P-path moved entirely into registers:
//  - stage C computes S^T = mfma(kf, qf) (same v4 fragments, swapped operands)
//    -> softmax over m is 16 in-lane values + TWO shfl_xor (v4 needed 128
//    cross-lane DS ops in 8-deep chains)
//  - P normalized+packed in-register (pk2, v5-proven) and redistributed into
//    PV A-fragments via the v10-proven quad-gather (no LDS round-trip,
//    no C-mid barrier)
// Stages A/B/E and all LDS layouts byte-identical to v4.
// launch_bounds(256,2): VGPR cap ~128 (4-waves/SIMD bucket), LDS caps 4 blk/CU.

#define NTOK 49
#define DIMC 128
#define HEADS 4
#define NWM  1024
#define SCALE 0.17677669529663687f

typedef __attribute__((ext_vector_type(8))) __bf16 bf16x8;
typedef __attribute__((ext_vector_type(4))) float f32x4;

// LDS map (bytes) -- identical to v4:
//  R1 [0,25088):     Q bf16 [4][49] rows 64B @0, K @12544 (stage B->C)
//  R2 [25088,39424): XB [49][256B] (A -> af loads)
//                    VT [4][32] rows 112B (B -> D, aliases XB after af loads)
//                    AO [49][256B] (D -> E, aliases VT after vb reads)
//  [39424,39440):    16B pad: VT row-127 kk=1/lg=3 overflow read (zeroed)
#define OFF_Q  0
#define OFF_K  12544
#define OFF_XB 25088
#define OFF_VT 25088
#define OFF_AO 25088
#define SMEM_BYTES 39440

__device__ __forceinline__ unsigned short f2bf(float f) {
  union { float f; unsigned u; } x; x.f = f;
  unsigned r = x.u + 0x7fffu + ((x.u >> 16) & 1u);   // round-to-nearest-even
  return (unsigned short)(r >> 16);
}

// packed f32x2 -> bf16x2 (low half = first arg), RTNE (v5/v10-proven)
__device__ __forceinline__ unsigned pk2(float a, float b) {
  __hip_bfloat162 t = __float22bfloat162_rn(make_float2(a, b));
  union { __hip_bfloat162 h; unsigned u; } c; c.h = t;
  return c.u;
}

__device__ __forceinline__ f32x4 mfma16(bf16x8 a, bf16x8 b, f32x4 c) {
  return __builtin_amdgcn_mfma_f32_16x16x32_bf16(a, b, c, 0, 0, 0);
}

__device__ __forceinline__ bf16x8 zero8() {
  bf16x8 z;
#pragma unroll
  for (int j = 0; j < 8; ++j) z[j] = (__bf16)0.f;
  return z;
}

// prep: weights -> bf16; rel-pos bias pre-gathered into padded [4][64][64] f32
// with -1e30 outside the 49x49 valid square (kills padding through softmax).
__global__ void winattn_prep(const float* __restrict__ qkv_w,
                             const float* __restrict__ proj_w,
                             const float* __restrict__ table,
                             const int* __restrict__ ridx,
                             unsigned short* __restrict__ qkv_wb,
                             unsigned short* __restrict__ proj_wb,
                             float* __restrict__ bias_g) {
  int i = blockIdx.x * 256 + threadIdx.x;
  if (i < 384 * DIMC) qkv_wb[i] = f2bf(qkv_w[i]);
  if (i < DIMC * DIMC) proj_wb[i] = f2bf(proj_w[i]);
  if (i < HEADS * 64 * 64) {
    int h = i >> 12, n = (i >> 6) & 63, m = i & 63;
    float v = -1e30f;
    if (n < NTOK && m < NTOK) v = table[ridx[n * NTOK + m] * HEADS + h];
    bias_g[i] = v;
  }
}

__launch_bounds__(256, 2)
__global__ void winattn_main(const float* __restrict__ x,
                             const float* __restrict__ mask,
                             const unsigned short* __restrict__ qkv_wb,
                             const float* __restrict__ qkv_b,
                             const unsigned short* __restrict__ proj_wb,
                             const float* __restrict__ proj_b,
                             const float* __restrict__ bias_g,
                             float* __restrict__ out) {
  __shared__ char smem[SMEM_BYTES] __attribute__((aligned(128)));
  const int tid  = threadIdx.x;
  const int w    = blockIdx.x;
  const int lane = tid & 63;
  const int wid  = tid >> 6;
  const int lr   = lane & 15;
  const int lg   = lane >> 4;
  const f32x4 fzero = {0.f, 0.f, 0.f, 0.f};

  const float* xw = x + (size_t)w * (NTOK * DIMC);

  // ---------- Stage A: x -> XB bf16, 49 rows (v4 verbatim) ----------------
  for (int i = tid; i < NTOK * 16; i += 256) {
    int n = i >> 4, c8 = i & 15;                       // 8-float chunk
    float4 v0 = *reinterpret_cast<const float4*>(xw + n * DIMC + c8 * 8);
    float4 v1 = *reinterpret_cast<const float4*>(xw + n * DIMC + c8 * 8 + 4);
    uint4 d;
    d.x = (unsigned)f2bf(v0.x) | ((unsigned)f2bf(v0.y) << 16);
    d.y = (unsigned)f2bf(v0.z) | ((unsigned)f2bf(v0.w) << 16);
    d.z = (unsigned)f2bf(v1.x) | ((unsigned)f2bf(v1.y) << 16);
    d.w = (unsigned)f2bf(v1.z) | ((unsigned)f2bf(v1.w) << 16);
    int mb = (c8 * 16) ^ ((n & 7) << 4);               // XOR-swizzle, 256B rows
    *reinterpret_cast<uint4*>(smem + OFF_XB + n * 256 + mb) = d;
  }
  if (tid == 0)   // zero the 16B tail pad (VT row-127 overflow-read target)
    *reinterpret_cast<uint4*>(smem + SMEM_BYTES - 16) = make_uint4(0u, 0u, 0u, 0u);
  __syncthreads();

  // ---------- af fragments (v4 verbatim) ----------------------------------
  bf16x8 af[4][4];
#pragma unroll
  for (int mt = 0; mt < 4; ++mt)
#pragma unroll
    for (int kk = 0; kk < 4; ++kk) {
      int n = mt * 16 + lr;
      bool pad = (n > 48);
      if (pad) n = 48;
      int mb = (kk * 64 + 16 * lg) ^ ((n & 7) << 4);
      bf16x8 v = *reinterpret_cast<const bf16x8*>(smem + OFF_XB + n * 256 + mb);
      af[mt][kk] = pad ? zero8() : v;
    }
  __syncthreads();   // XB dead; VT writes (aliasing XB) may proceed

  // ---------- Stage B: QKV (v4 verbatim) ----------------------------------
  {
    const int cb = wid * 96;  // each wave owns 96 output cols (6 N-tiles)
#pragma unroll
    for (int nt = 0; nt < 6; ++nt) {
      const int o = cb + nt * 16 + lr;  // global qkv col for this lane
      const unsigned short* wrow = qkv_wb + o * DIMC;
      bf16x8 bf[4];
#pragma unroll
      for (int kk = 0; kk < 4; ++kk)
        bf[kk] = *reinterpret_cast<const bf16x8*>(wrow + kk * 32 + lg * 8);
      f32x4 acc[4];
#pragma unroll
      for (int mt = 0; mt < 4; ++mt) acc[mt] = fzero;
#pragma unroll
      for (int kk = 0; kk < 4; ++kk)
#pragma unroll
        for (int mt = 0; mt < 4; ++mt)
          acc[mt] = mfma16(af[mt][kk], bf[kk], acc[mt]);
      const float bq = qkv_b[o];
      const int s  = o >> 7;            // 0=q 1=k 2=v (uniform per tile)
      const int h2 = (o & 127) >> 5;    // head (uniform per tile)
      const int d  = o & 31;
#pragma unroll
      for (int mt = 0; mt < 4; ++mt)
#pragma unroll
        for (int r = 0; r < 4; ++r) {
          const int n = mt * 16 + lg * 4 + r;
          const unsigned short bv = f2bf(acc[mt][r] + bq);
          if (s == 2) {
            if (n < 56)   // VT[h2][d][n], 112B rows, unswizzled
              *reinterpret_cast<unsigned short*>(
                  smem + OFF_VT + (h2 * 32 + d) * 112 + n * 2) = bv;
          } else if (n < NTOK) {
            int base = (s == 0) ? OFF_Q : OFF_K;
            int mb = (d * 2) ^ ((n & 3) << 4);
            *reinterpret_cast<unsigned short*>(
                smem + base + (h2 * NTOK + n) * 64 + mb) = bv;
          }
        }
    }
  }
  __syncthreads();   // Q/K/VT written cross-wave -> barrier before stage C

  // ---------- Stage C: S^T = mfma(K, Q), bias+mask, in-lane softmax -------
  const int h = wid;
  bf16x8 pa[4][2];            // PV A-fragments, built in-register from P
  {
    bf16x8 qf[4], kf[4];
#pragma unroll
    for (int mt = 0; mt < 4; ++mt) {
      int n = mt * 16 + lr; if (n > 48) n = 48;   // clamp padded rows
      int mb = (lg * 16) ^ ((n & 3) << 4);
      qf[mt] = *reinterpret_cast<const bf16x8*>(smem + OFF_Q + (h * NTOK + n) * 64 + mb);
    }
#pragma unroll
    for (int nt = 0; nt < 4; ++nt) {
      int m = nt * 16 + lr; if (m > 48) m = 48;
      int mb = (lg * 16) ^ ((m & 3) << 4);
      kf[nt] = *reinterpret_cast<const bf16x8*>(smem + OFF_K + (h * NTOK + m) * 64 + mb);
    }
    // S^T: rows = m (kf index), cols = n (qf index)
    f32x4 sc[4][4];
#pragma unroll
    for (int mi = 0; mi < 4; ++mi)
#pragma unroll
      for (int ni = 0; ni < 4; ++ni)
        sc[mi][ni] = mfma16(kf[mi], qf[ni], fzero);

    // fold scale + bias + mask: sc[mi][ni][r] = S[n=ni*16+lr][m=mi*16+lg*4+r]
    const float* bgh = bias_g + h * 4096;
    const float* mw  = mask + (size_t)(w & (NWM - 1)) * (NTOK * NTOK);
#pragma unroll
    for (int mi = 0; mi < 4; ++mi) {
      const int m0 = mi * 16 + lg * 4;
#pragma unroll
      for (int ni = 0; ni < 4; ++ni) {
        const int n  = ni * 16 + lr;
        const int nc = (n > 48) ? 48 : n;
        float4 bg = *reinterpret_cast<const float4*>(bgh + n * 64 + m0);  // 16B-aligned
        float4 mk;
        if (mi < 3) {
          mk.x = mw[nc * NTOK + m0];     mk.y = mw[nc * NTOK + m0 + 1];
          mk.z = mw[nc * NTOK + m0 + 2]; mk.w = mw[nc * NTOK + m0 + 3];
        } else {
          float ms = mw[nc * NTOK + 48];  // m0 in {48,52,56,60}: all clamp to 48
          mk.x = ms; mk.y = ms; mk.z = ms; mk.w = ms;
        }
        sc[mi][ni][0] = sc[mi][ni][0] * SCALE + bg.x + mk.x;
        sc[mi][ni][1] = sc[mi][ni][1] * SCALE + bg.y + mk.y;
        sc[mi][ni][2] = sc[mi][ni][2] * SCALE + bg.z + mk.z;
        sc[mi][ni][3] = sc[mi][ni][3] * SCALE + bg.w + mk.w;
      }
    }
    // softmax over m, per col n: 16 in-lane + shfl_xor(16) + shfl_xor(32).
    // padded m rows carry bias=-1e30 -> exp 0; padded n cols are finite
    // garbage, discarded by the n<NTOK guard at the AO store.
    uint2 pk[4][4];   // pk[mi][ni] = P[n][m0..m0+3] packed bf16
#pragma unroll
    for (int ni = 0; ni < 4; ++ni) {
      float mx = sc[0][ni][0];
#pragma unroll
      for (int mi = 0; mi < 4; ++mi)
#pragma unroll
        for (int r = 0; r < 4; ++r) mx = fmaxf(mx, sc[mi][ni][r]);
      mx = fmaxf(mx, __shfl_xor(mx, 16));
      mx = fmaxf(mx, __shfl_xor(mx, 32));
      float sum = 0.f;
#pragma unroll
      for (int mi = 0; mi < 4; ++mi)
#pragma unroll
        for (int r = 0; r < 4; ++r) {
          sc[mi][ni][r] = __expf(sc[mi][ni][r] - mx);
          sum += sc[mi][ni][r];
        }
      sum += __shfl_xor(sum, 16);
      sum += __shfl_xor(sum, 32);
      const float inv = __builtin_amdgcn_rcpf(sum);
#pragma unroll
      for (int mi = 0; mi < 4; ++mi) {
        pk[mi][ni].x = pk2(sc[mi][ni][0] * inv, sc[mi][ni][1] * inv);
        pk[mi][ni].y = pk2(sc[mi][ni][2] * inv, sc[mi][ni][3] * inv);
      }
    }
    // quad-gather (v10-proven algebra): lane(lr,lg) wants
    // P[n = ni*16+lr][m = kk*32 + lg*8 .. +7] as A-fragment bf16x8
    const int srcLow  = lr + ((lg & 1) ? 32 : 0);
    const int srcHigh = srcLow + 16;
    const bool hiSel  = (lg >> 1) != 0;
#pragma unroll
    for (int ni = 0; ni < 4; ++ni)
#pragma unroll
      for (int kk = 0; kk < 2; ++kk) {
        unsigned a0x = __shfl(pk[kk * 2][ni].x, srcLow);
        unsigned a0y = __shfl(pk[kk * 2][ni].y, srcLow);
        unsigned a1x = __shfl(pk[kk * 2 + 1][ni].x, srcLow);
        unsigned a1y = __shfl(pk[kk * 2 + 1][ni].y, srcLow);
        unsigned b0x = __shfl(pk[kk * 2][ni].x, srcHigh);
        unsigned b0y = __shfl(pk[kk * 2][ni].y, srcHigh);
        unsigned b1x = __shfl(pk[kk * 2 + 1][ni].x, srcHigh);
        unsigned b1y = __shfl(pk[kk * 2 + 1][ni].y, srcHigh);
        union { uint4 u; bf16x8 b; } cvt;
        cvt.u.x = hiSel ? a1x : a0x;
        cvt.u.y = hiSel ? a1y : a0y;
        cvt.u.z = hiSel ? b1x : b0x;
        cvt.u.w = hiSel ? b1y : b0y;
        pa[ni][kk] = cvt.b;
      }
  }
  // P never touched LDS -> no barrier

  // ---------- Stage D: PV with register-P (vb from VT, v4 verbatim) -------
  {
    bf16x8 vb[2][2];
#pragma unroll
    for (int dt = 0; dt < 2; ++dt)
#pragma unroll
      for (int kk = 0; kk < 2; ++kk) {
        const int d = dt * 16 + lr;
        vb[dt][kk] = *reinterpret_cast<const bf16x8*>(
            smem + OFF_VT + (h * 32 + d) * 112 + kk * 64 + 16 * lg);
      }
    f32x4 oc[4][2];
#pragma unroll
    for (int mt = 0; mt < 4; ++mt)
#pragma unroll
      for (int dt = 0; dt < 2; ++dt) oc[mt][dt] = fzero;
#pragma unroll
    for (int kk = 0; kk < 2; ++kk)
#pragma unroll
      for (int mt = 0; mt < 4; ++mt)
#pragma unroll
        for (int dt = 0; dt < 2; ++dt)
          oc[mt][dt] = mfma16(pa[mt][kk], vb[dt][kk], oc[mt][dt]);
    __syncthreads();   // all VT reads done -> AO may overwrite VT
#pragma unroll
    for (int mt = 0; mt < 4; ++mt)
#pragma unroll
      for (int dt = 0; dt < 2; ++dt)
#pragma unroll
        for (int r = 0; r < 4; ++r) {
          const int n = mt * 16 + lg * 4 + r;
          if (n < NTOK) {
            const int c = h * 32 + dt * 16 + lr;
            int mb = (c * 2) ^ ((n & 7) << 4);
            *reinterpret_cast<unsigned short*>(smem + OFF_AO + n * 256 + mb) =
                f2bf(oc[mt][dt][r]);
          }
        }
  }
  __syncthreads();

  // ---------- Stage E: proj = AO @ proj_w^T + proj_b (v4 verbatim) --------
  {
    bf16x8 aof[4][4];
#pragma unroll
    for (int mt = 0; mt < 4; ++mt)
#pragma unroll
      for (int kk = 0; kk < 4; ++kk) {
        int n = mt * 16 + lr; if (n > 48) n = 48;      // keep in AO bounds
        int s16 = 4 * kk + lg;
        aof[mt][kk] = *reinterpret_cast<const bf16x8*>(
            smem + OFF_AO + n * 256 + (((s16 & 8) | ((s16 ^ (n & 7)) & 7)) << 4));
      }
    float* ow = out + (size_t)w * (NTOK * DIMC);
#pragma unroll
    for (int ct = 0; ct < 2; ++ct) {
      const int c = (wid * 2 + ct) * 16 + lr;  // each wave owns 32 cols
      const unsigned short* wrow = proj_wb + c * DIMC;
      bf16x8 wb[4];
#pragma unroll
      for (int kk = 0; kk < 4; ++kk)
        wb[kk] = *reinterpret_cast<const bf16x8*>(wrow + kk * 32 + lg * 8);
      f32x4 acc[4];
#pragma unroll
      for (int mt = 0; mt < 4; ++mt) acc[mt] = fzero;
#pragma unroll
      for (int kk = 0; kk < 4; ++kk)
#pragma unroll
        for (int mt = 0; mt < 4; ++mt)
          acc[mt] = mfma16(aof[mt][kk], wb[kk], acc[mt]);
      const float bp = proj_b[c];
#pragma unroll
      for (int mt = 0; mt < 4; ++mt)
#pragma unroll
        for (int r = 0; r < 4; ++r) {
          const int n = mt * 16 + lg * 4 + r;
          if (n < NTOK) ow[n * DIMC + c] = acc[mt][r] + bp;
        }
    }
  }
}

extern "C" void kernel_launch(void* const* d_in, const int* in_sizes, int n_in,
                              void* d_out, int out_size, void* d_ws, size_t ws_size,
                              hipStream_t stream) {
  const float* x      = (const float*)d_in[0];
  const float* mask   = (const float*)d_in[1];
  const float* qkv_w  = (const float*)d_in[2];
  const float* qkv_b  = (const float*)d_in[3];
  const float* proj_w = (const float*)d_in[4];
  const float* proj_b = (const float*)d_in[5];
  const float* table  = (const float*)d_in[6];
  const int*   ridx   = (const int*)d_in[7];

  unsigned short* qkv_wb  = (unsigned short*)d_ws;           // 384*128 bf16
  unsigned short* proj_wb = qkv_wb + 384 * DIMC;             // 128*128 bf16
  float*          bias_g  = (float*)(proj_wb + DIMC * DIMC); // [4][64][64] f32

  winattn_prep<<<192, 256, 0, stream>>>(qkv_w, proj_w, table, ridx,
                                        qkv_wb, proj_wb, bias_g);

  const int nwin = in_sizes[0] / (NTOK * DIMC);
  winattn_main<<<nwin, 256, 0, stream>>>(x, mask, qkv_wb, qkv_b, proj_wb,
                                         proj_b, bias_g, (float*)d_out);
}